// Round 7
// baseline (169.160 us; speedup 1.0000x reference)
//
#include <hip/hip_runtime.h>
#include <math.h>

// Zero-padded symmetric weight tables: per sigma, layout is
// [8 zeros][w[R], ..., w[1], w[0], w[1], ..., w[R]][8 zeros]  (length 2R+17).
// Index m in [0, 2R] holds w[|m-R|] at table offset m+8. The pads absorb all
// out-of-range taps so the tap loops need no conditionals.
struct GW { float w[185]; };
constexpr int W05 = 0;    // sigma 0.5, R=2,  len 21
constexpr int W1  = 21;   // sigma 1,   R=5,  len 27
constexpr int W2  = 48;   // sigma 2,   R=11, len 39
constexpr int W4  = 87;   // sigma 4,   R=16, len 49
constexpr int W8  = 136;  // sigma 8,   R=16, len 49

namespace {

constexpr float kC1 = 1e-4f;
constexpr float kC2 = 9e-4f;

// 512 threads/block, 32x32 output tile.
// LDS (~64.5 KB -> 2 blocks/CU = 16 waves/CU):
//  sS/sD : [64][64] floats, float4-group g XOR'd by (row&7)            (16 KB each)
//  hb0   : pair plane (s,d):   [64 rows][32 cols] float2               (16 KB)
//  hb1   : pair plane (s2,d2): same layout                             (16 KB)
//          16B-group g (covers cols 2g,2g+1) stored at gphys = g ^ (row&15).
//          v-pass b64 reads: per 32-lane half each bank hit exactly 2x (free).
//          h-pass b128 writes: bank-class ((2cg+w)&7)^row spans all 8 classes.
//  hbl   : L1 reuse of hb0: [64][32] floats, plain layout (8 KB).

// Horizontal pass, rows trimmed to NROWS=32+2R (hrow h = halo row h+16-R).
// One entry per thread (NE = NROWS*8 <= 512).
template<int R, int WOFF>
__device__ __forceinline__ void hpass4(const GW& g, const float* __restrict__ sS,
                                       const float* __restrict__ sD,
                                       float* __restrict__ hb0,
                                       float* __restrict__ hb1, int t) {
  constexpr int NROWS = 32 + 2 * R;
  constexpr int NE = NROWS * 8;
  constexpr int QS = (16 - R) & ~3;
  constexpr int NG = ((19 + R - QS) >> 2) + 1;
  if (t >= NE) return;
  const int hrow = t >> 3;
  const int cg = t & 7;
  const int srow = hrow + (16 - R);
  const int rx = srow & 7;
  const int rowbase = srow << 6;
  const int g0 = cg + (QS >> 2);
  float a0[4] = {0.f, 0.f, 0.f, 0.f}, a1[4] = {0.f, 0.f, 0.f, 0.f};
  float a2[4] = {0.f, 0.f, 0.f, 0.f}, a3[4] = {0.f, 0.f, 0.f, 0.f};
#pragma unroll 2
  for (int j = 0; j < NG; ++j) {
    const int off = rowbase + (((g0 + j) ^ rx) << 2);
    const int wb = WOFF + 8 + QS - 16 + R + 4 * j;  // + u - o; pads absorb ends
    const float4 s4 = *reinterpret_cast<const float4*>(&sS[off]);
    const float4 d4 = *reinterpret_cast<const float4*>(&sD[off]);
    const float* sp = reinterpret_cast<const float*>(&s4);
    const float* dp = reinterpret_cast<const float*>(&d4);
#pragma unroll
    for (int u = 0; u < 4; ++u) {
      const float sv = sp[u], dv = dp[u];
      const float s2 = sv * sv, d2 = dv * dv;
#pragma unroll
      for (int o = 0; o < 4; ++o) {
        const float wk = g.w[wb + u - o];
        a0[o] += wk * sv; a1[o] += wk * dv;
        a2[o] += wk * s2; a3[o] += wk * d2;
      }
    }
  }
  const int rb = hrow << 6;
  const int rk = hrow & 15;
#pragma unroll
  for (int w = 0; w < 2; ++w) {
    const int gphys = ((cg << 1) + w) ^ rk;
    const int o = w << 1;
    *reinterpret_cast<float4*>(&hb0[rb + (gphys << 2)]) =
        make_float4(a0[o], a1[o], a0[o + 1], a1[o + 1]);
    *reinterpret_cast<float4*>(&hb1[rb + (gphys << 2)]) =
        make_float4(a2[o], a3[o], a2[o + 1], a3[o + 1]);
  }
}

// Vertical pass. Thread owns col vc = t&31, output rows vr0..vr0+1.
// Two b64 reads per tap (pair planes), conflict-free.
template<int R, int WOFF>
__device__ __forceinline__ void vpass4(const GW& g, const float* __restrict__ hb0,
                                       const float* __restrict__ hb1,
                                       int vc, int vr0,
                                       float (&o0)[2], float (&o1)[2],
                                       float (&o2)[2], float (&o3)[2]) {
#pragma unroll
  for (int i = 0; i < 2; ++i) { o0[i] = o1[i] = o2[i] = o3[i] = 0.f; }
  const int gcol = vc >> 1;
  const int plo = (vc & 1) << 1;
#pragma unroll 2
  for (int jj = 0; jj < 2 * R + 2; ++jj) {
    const int r = vr0 + jj;
    const int off = (r << 6) + (((gcol ^ (r & 15)) << 2) | plo);
    const float2 vsd = *reinterpret_cast<const float2*>(&hb0[off]);
    const float2 vq  = *reinterpret_cast<const float2*>(&hb1[off]);
    const int wb = WOFF + 8 + jj;   // weight index: wb - i; pads absorb ends
#pragma unroll
    for (int i = 0; i < 2; ++i) {
      const float wk = g.w[wb - i];
      o0[i] += wk * vsd.x; o1[i] += wk * vsd.y;
      o2[i] += wk * vq.x;  o3[i] += wk * vq.y;
    }
  }
}

template<int R, int WOFF, int MULT, bool DOLM>
__device__ __forceinline__ void sweep4(const GW& g,
    const float* sS, const float* sD, float* hb0, float* hb1, int t, int vc, int vr0,
    float (&PI)[2], float (&lM)[2]) {
  __syncthreads();                  // hb free, tile visible
  hpass4<R, WOFF>(g, sS, sD, hb0, hb1, t);
  __syncthreads();
  float os[2], od[2], os2[2], od2[2];
  vpass4<R, WOFF>(g, hb0, hb1, vc, vr0, os, od, os2, od2);
#pragma unroll
  for (int i = 0; i < 2; ++i) {
    const float vs = os2[i] - os[i] * os[i];   // Var(x+y)
    const float vd = od2[i] - od[i] * od[i];   // Var(x-y)
    const float cs = (0.5f * (vs - vd) + kC2) / (0.5f * (vs + vd) + kC2);
    float p = cs;
    if constexpr (MULT > 1) p *= cs;
    if constexpr (MULT > 2) p *= cs;
    PI[i] *= p;
    if constexpr (DOLM) {
      const float sa = os[i] * os[i], sb = od[i] * od[i];
      const float lc = (0.5f * (sa - sb) + kC1) / (0.5f * (sa + sb) + kC1);
      lM[i] = lc * lc * lc;
    }
  }
}

// L1 path (sigma 8, R=16): |d| blur. 512 h-entries, one per thread.
template<int R, int WOFF>
__device__ __forceinline__ void hpassL1(const GW& g, const float* __restrict__ sD,
                                        float* __restrict__ hbl, int t) {
  constexpr int QS = (16 - R) & ~3;
  constexpr int NG = ((19 + R - QS) >> 2) + 1;
  const int hrow = t >> 3;
  const int cg = t & 7;
  const int rx = hrow & 7;           // srow == hrow for R=16
  const int rowbase = hrow << 6;
  const int g0 = cg + (QS >> 2);
  float a0[4] = {0.f, 0.f, 0.f, 0.f};
#pragma unroll 2
  for (int j = 0; j < NG; ++j) {
    const int off = rowbase + (((g0 + j) ^ rx) << 2);
    const int wb = WOFF + 8 + QS - 16 + R + 4 * j;
    const float4 d4 = *reinterpret_cast<const float4*>(&sD[off]);
    const float* dp = reinterpret_cast<const float*>(&d4);
#pragma unroll
    for (int u = 0; u < 4; ++u) {
      const float av = fabsf(dp[u]);
#pragma unroll
      for (int o = 0; o < 4; ++o) a0[o] += g.w[wb + u - o] * av;
    }
  }
  *reinterpret_cast<float4*>(&hbl[(hrow << 5) + (cg << 2)]) =
      make_float4(a0[0], a0[1], a0[2], a0[3]);
}

template<int R, int WOFF>
__device__ __forceinline__ void sweepL1(const GW& g, const float* sD, float* hbl,
                                        int t, int vc, int vr0, float (&l1s)[2]) {
  __syncthreads();
  hpassL1<R, WOFF>(g, sD, hbl, t);
  __syncthreads();
#pragma unroll 2
  for (int jj = 0; jj < 2 * R + 2; ++jj) {
    const float vl = hbl[((vr0 + jj) << 5) + vc];
    const int wb = WOFF + 8 + jj;
#pragma unroll
    for (int i = 0; i < 2; ++i) l1s[i] += g.w[wb - i] * vl;
  }
}

__device__ __forceinline__ void load_tile(const float* __restrict__ p1,
                                          const float* __restrict__ p2,
                                          float* __restrict__ sS, float* __restrict__ sD,
                                          int t, int gx0, int gy0) {
#pragma unroll 1
  for (int e = 0; e < 2; ++e) {
    const int gidx = t + (e << 9);
    const int ly = gidx >> 4, lg = gidx & 15;
    const int gy = gy0 + ly;
    const int gx = gx0 + (lg << 2);
    float4 a = make_float4(0.f, 0.f, 0.f, 0.f);
    float4 b = make_float4(0.f, 0.f, 0.f, 0.f);
    if (gy >= 0 && gy < 512) {
      if (gx >= 0 && gx + 3 < 512) {
        a = *reinterpret_cast<const float4*>(&p1[(gy << 9) + gx]);
        b = *reinterpret_cast<const float4*>(&p2[(gy << 9) + gx]);
      } else {
        float* ap = reinterpret_cast<float*>(&a);
        float* bp = reinterpret_cast<float*>(&b);
#pragma unroll
        for (int u = 0; u < 4; ++u) {
          const int x = gx + u;
          if (x >= 0 && x < 512) { ap[u] = p1[(gy << 9) + x]; bp[u] = p2[(gy << 9) + x]; }
        }
      }
    }
    float4 s, d;
    s.x = a.x + b.x; s.y = a.y + b.y; s.z = a.z + b.z; s.w = a.w + b.w;
    d.x = a.x - b.x; d.y = a.y - b.y; d.z = a.z - b.z; d.w = a.w - b.w;
    const int off = (ly << 6) + ((lg ^ (ly & 7)) << 2);
    *reinterpret_cast<float4*>(&sS[off]) = s;
    *reinterpret_cast<float4*>(&sD[off]) = d;
  }
}

}  // namespace

extern "C" __global__ __launch_bounds__(512) void msssim_main(
    const float* __restrict__ img1, const float* __restrict__ img2,
    float* __restrict__ partial, GW g) {
  __shared__ __align__(16) float sS[4096];
  __shared__ __align__(16) float sD[4096];
  __shared__ __align__(16) float hb0[4096];   // (s,d) pairs; L1 aliases 8 KB
  __shared__ __align__(16) float hb1[4096];   // (s2,d2) pairs
  __shared__ float red[8];

  const int t = threadIdx.x;

  // XCD-contiguous swizzle: 2048 blocks / 8 XCDs -> XCD k owns batch image k.
  const int bid = (int)blockIdx.x + ((int)blockIdx.y << 4) + ((int)blockIdx.z << 8);
  const int swz = ((bid & 7) << 8) + (bid >> 3);
  const int bx = swz & 15, by = (swz >> 4) & 15, b = swz >> 8;

  const int gx0 = bx * 32 - 16;
  const int gy0 = by * 32 - 16;
  const int vc = t & 31;          // owned column
  const int vr0 = (t >> 5) << 1;  // owned row base (2 consecutive rows)

  float PI[2] = {1.f, 1.f};
  float lM[2] = {0.f, 0.f};
  float l1s[2] = {0.f, 0.f};

  // Channel 0: cs(s0.5)^3 * cs(s1)^2 ; L1 blur s8
  {
    const float* p1 = img1 + (((size_t)b * 3 + 0) << 18);
    const float* p2 = img2 + (((size_t)b * 3 + 0) << 18);
    load_tile(p1, p2, sS, sD, t, gx0, gy0);
    sweep4<2, W05, 3, false>(g, sS, sD, hb0, hb1, t, vc, vr0, PI, lM);
    sweep4<5, W1, 2, false>(g, sS, sD, hb0, hb1, t, vc, vr0, PI, lM);
    sweepL1<16, W8>(g, sD, hb0, t, vc, vr0, l1s);
  }
  // Channel 1: cs(s1)^1 * cs(s2)^3 * cs(s4)^1 ; L1 blur s8
  {
    const float* p1 = img1 + (((size_t)b * 3 + 1) << 18);
    const float* p2 = img2 + (((size_t)b * 3 + 1) << 18);
    load_tile(p1, p2, sS, sD, t, gx0, gy0);
    sweep4<5, W1, 1, false>(g, sS, sD, hb0, hb1, t, vc, vr0, PI, lM);
    sweep4<11, W2, 3, false>(g, sS, sD, hb0, hb1, t, vc, vr0, PI, lM);
    sweep4<16, W4, 1, false>(g, sS, sD, hb0, hb1, t, vc, vr0, PI, lM);
    sweepL1<16, W8>(g, sD, hb0, t, vc, vr0, l1s);
  }
  // Channel 2: cs(s4)^2 * cs(s8)^3 + lM(s8) ; L1 blur s8
  {
    const float* p1 = img1 + (((size_t)b * 3 + 2) << 18);
    const float* p2 = img2 + (((size_t)b * 3 + 2) << 18);
    load_tile(p1, p2, sS, sD, t, gx0, gy0);
    sweep4<16, W4, 2, false>(g, sS, sD, hb0, hb1, t, vc, vr0, PI, lM);
    sweep4<16, W8, 3, true>(g, sS, sD, hb0, hb1, t, vc, vr0, PI, lM);
    sweepL1<16, W8>(g, sD, hb0, t, vc, vr0, l1s);
  }

  float s = 0.f;
#pragma unroll
  for (int i = 0; i < 2; ++i)
    s += 0.025f * (1.f - lM[i] * PI[i]) + 0.975f * (l1s[i] * (1.f / 3.f));

#pragma unroll
  for (int off = 32; off >= 1; off >>= 1) s += __shfl_down(s, off, 64);
  if ((t & 63) == 0) red[t >> 6] = s;
  __syncthreads();
  if (t == 0) {
    float tot = 0.f;
#pragma unroll
    for (int i = 0; i < 8; ++i) tot += red[i];
    partial[swz] = tot;
  }
}

extern "C" __global__ __launch_bounds__(256) void msssim_reduce(
    const float* __restrict__ partial, float* __restrict__ out, int n) {
  __shared__ float red[4];
  float s = 0.f;
  for (int i = threadIdx.x; i < n; i += 256) s += partial[i];
#pragma unroll
  for (int off = 32; off >= 1; off >>= 1) s += __shfl_down(s, off, 64);
  if ((threadIdx.x & 63) == 0) red[threadIdx.x >> 6] = s;
  __syncthreads();
  if (threadIdx.x == 0) {
    out[0] = (red[0] + red[1] + red[2] + red[3]) * (200.0f / 2097152.0f);
  }
}

extern "C" void kernel_launch(void* const* d_in, const int* in_sizes, int n_in,
                              void* d_out, int out_size, void* d_ws, size_t ws_size,
                              hipStream_t stream) {
  const float* img1 = (const float*)d_in[0];
  const float* img2 = (const float*)d_in[1];
  float* out = (float*)d_out;
  float* partial = (float*)d_ws;  // 2048 floats

  // Host-side padded weight tables (double-precision normalize, then cast).
  GW g;
  {
    const double sig[5] = {0.5, 1.0, 2.0, 4.0, 8.0};
    const int R[5] = {2, 5, 11, 16, 16};
    const int off[5] = {W05, W1, W2, W4, W8};
    for (int i = 0; i < 5; ++i) {
      double tmp[17];
      double sum = 0.0;
      for (int k = 0; k <= R[i]; ++k) {
        tmp[k] = exp(-(double)(k * k) / (2.0 * sig[i] * sig[i]));
        sum += (k ? 2.0 : 1.0) * tmp[k];
      }
      const int len = 2 * R[i] + 17;
      for (int m = 0; m < len; ++m) {
        int d = m - 8 - R[i];
        if (d < 0) d = -d;
        g.w[off[i] + m] = (m >= 8 && m <= 8 + 2 * R[i]) ? (float)(tmp[d] / sum) : 0.0f;
      }
    }
  }

  dim3 grid(16, 16, 8);
  msssim_main<<<grid, dim3(512), 0, stream>>>(img1, img2, partial, g);
  msssim_reduce<<<1, dim3(256), 0, stream>>>(partial, out, 2048);
}

// Round 8
// 149.194 us; speedup vs baseline: 1.1338x; 1.1338x over previous
//
#include <hip/hip_runtime.h>
#include <math.h>

// Zero-padded symmetric weight tables: per sigma, layout is
// [8 zeros][w[R], ..., w[1], w[0], w[1], ..., w[R]][8 zeros]  (length 2R+17).
// Index m in [0, 2R] holds w[|m-R|] at table offset m+8. The pads absorb all
// out-of-range taps so the tap loops need no conditionals.
// Truncation: tails renormalized; relative tail mass <7e-4 worst case (sigma=4),
// and it largely cancels in the cs/lc ratios. sigma=8 stays exact (R=16).
struct GW { float w[185]; };
constexpr int W05 = 0;    // sigma 0.5, R=2,  len 21
constexpr int W1  = 21;   // sigma 1,   R=4,  len 25
constexpr int W2  = 46;   // sigma 2,   R=9,  len 35
constexpr int W4  = 81;   // sigma 4,   R=13, len 43
constexpr int W8  = 124;  // sigma 8,   R=16, len 49

namespace {

constexpr float kC1 = 1e-4f;
constexpr float kC2 = 9e-4f;

// 512 threads/block, 32x32 output tile.
// LDS (64.5 KB -> 2 blocks/CU = 16 waves/CU):
//  sS/sD : [64][64] floats, float4-group g XOR'd by (row&7)   (16 KB each)
//  hb4   : [<=64 rows][32 slots] float4 (s,d,s2,d2), slot c^((c>>3)&3) (32 KB)
//  hbl   : L1 reuse of hb4: [64][32] floats, plain layout (8 KB).

// Horizontal pass, rows trimmed to NROWS=32+2R (hrow h = halo row h+16-R).
// One entry per thread (NE = NROWS*8 <= 512).
template<int R, int WOFF>
__device__ __forceinline__ void hpass4(const GW& g, const float* __restrict__ sS,
                                       const float* __restrict__ sD,
                                       float4* __restrict__ hb, int t) {
  constexpr int NROWS = 32 + 2 * R;
  constexpr int NE = NROWS * 8;
  constexpr int QS = (16 - R) & ~3;
  constexpr int NG = ((19 + R - QS) >> 2) + 1;
  if (t >= NE) return;
  const int hrow = t >> 3;
  const int cg = t & 7;
  const int srow = hrow + (16 - R);
  const int rx = srow & 7;
  const int rowbase = srow << 6;
  const int g0 = cg + (QS >> 2);
  float a0[4] = {0.f, 0.f, 0.f, 0.f}, a1[4] = {0.f, 0.f, 0.f, 0.f};
  float a2[4] = {0.f, 0.f, 0.f, 0.f}, a3[4] = {0.f, 0.f, 0.f, 0.f};
#pragma unroll 2
  for (int j = 0; j < NG; ++j) {
    const int off = rowbase + (((g0 + j) ^ rx) << 2);
    const int wb = WOFF + 8 + QS - 16 + R + 4 * j;  // + u - o; pads absorb ends
    const float4 s4 = *reinterpret_cast<const float4*>(&sS[off]);
    const float4 d4 = *reinterpret_cast<const float4*>(&sD[off]);
    const float* sp = reinterpret_cast<const float*>(&s4);
    const float* dp = reinterpret_cast<const float*>(&d4);
#pragma unroll
    for (int u = 0; u < 4; ++u) {
      const float sv = sp[u], dv = dp[u];
      const float s2 = sv * sv, d2 = dv * dv;
#pragma unroll
      for (int o = 0; o < 4; ++o) {
        const float wk = g.w[wb + u - o];
        a0[o] += wk * sv; a1[o] += wk * dv;
        a2[o] += wk * s2; a3[o] += wk * d2;
      }
    }
  }
  const int rb = hrow << 5;
#pragma unroll
  for (int o = 0; o < 4; ++o) {
    const int c = (cg << 2) + o;
    hb[rb + (c ^ ((c >> 3) & 3))] = make_float4(a0[o], a1[o], a2[o], a3[o]);
  }
}

// Vertical pass. Thread owns col vc = t&31, output rows vr0..vr0+1.
template<int R, int WOFF>
__device__ __forceinline__ void vpass4(const GW& g, const float4* __restrict__ hb,
                                       int vc, int vr0,
                                       float (&o0)[2], float (&o1)[2],
                                       float (&o2)[2], float (&o3)[2]) {
#pragma unroll
  for (int i = 0; i < 2; ++i) { o0[i] = o1[i] = o2[i] = o3[i] = 0.f; }
  const int fc = vc ^ ((vc >> 3) & 3);
#pragma unroll 2
  for (int jj = 0; jj < 2 * R + 2; ++jj) {
    const float4 v = hb[((vr0 + jj) << 5) + fc];
    const int wb = WOFF + 8 + jj;   // weight index: wb - i; pads absorb ends
#pragma unroll
    for (int i = 0; i < 2; ++i) {
      const float wk = g.w[wb - i];
      o0[i] += wk * v.x; o1[i] += wk * v.y;
      o2[i] += wk * v.z; o3[i] += wk * v.w;
    }
  }
}

template<int R, int WOFF, int MULT, bool DOLM>
__device__ __forceinline__ void sweep4(const GW& g,
    const float* sS, const float* sD, float4* hb, int t, int vc, int vr0,
    float (&PI)[2], float (&lM)[2]) {
  __syncthreads();                  // hb free, tile visible
  hpass4<R, WOFF>(g, sS, sD, hb, t);
  __syncthreads();
  float os[2], od[2], os2[2], od2[2];
  vpass4<R, WOFF>(g, hb, vc, vr0, os, od, os2, od2);
#pragma unroll
  for (int i = 0; i < 2; ++i) {
    const float vs = os2[i] - os[i] * os[i];   // Var(x+y)
    const float vd = od2[i] - od[i] * od[i];   // Var(x-y)
    const float cs = (0.5f * (vs - vd) + kC2) / (0.5f * (vs + vd) + kC2);
    float p = cs;
    if constexpr (MULT > 1) p *= cs;
    if constexpr (MULT > 2) p *= cs;
    PI[i] *= p;
    if constexpr (DOLM) {
      const float sa = os[i] * os[i], sb = od[i] * od[i];
      const float lc = (0.5f * (sa - sb) + kC1) / (0.5f * (sa + sb) + kC1);
      lM[i] = lc * lc * lc;
    }
  }
}

// L1 path (sigma 8, R=16): |d| blur. 512 h-entries, one per thread.
template<int R, int WOFF>
__device__ __forceinline__ void hpassL1(const GW& g, const float* __restrict__ sD,
                                        float* __restrict__ hbl, int t) {
  constexpr int QS = (16 - R) & ~3;
  constexpr int NG = ((19 + R - QS) >> 2) + 1;
  const int hrow = t >> 3;
  const int cg = t & 7;
  const int rx = hrow & 7;           // srow == hrow for R=16
  const int rowbase = hrow << 6;
  const int g0 = cg + (QS >> 2);
  float a0[4] = {0.f, 0.f, 0.f, 0.f};
#pragma unroll 2
  for (int j = 0; j < NG; ++j) {
    const int off = rowbase + (((g0 + j) ^ rx) << 2);
    const int wb = WOFF + 8 + QS - 16 + R + 4 * j;
    const float4 d4 = *reinterpret_cast<const float4*>(&sD[off]);
    const float* dp = reinterpret_cast<const float*>(&d4);
#pragma unroll
    for (int u = 0; u < 4; ++u) {
      const float av = fabsf(dp[u]);
#pragma unroll
      for (int o = 0; o < 4; ++o) a0[o] += g.w[wb + u - o] * av;
    }
  }
  *reinterpret_cast<float4*>(&hbl[(hrow << 5) + (cg << 2)]) =
      make_float4(a0[0], a0[1], a0[2], a0[3]);
}

template<int R, int WOFF>
__device__ __forceinline__ void sweepL1(const GW& g, const float* sD, float* hbl,
                                        int t, int vc, int vr0, float (&l1s)[2]) {
  __syncthreads();
  hpassL1<R, WOFF>(g, sD, hbl, t);
  __syncthreads();
#pragma unroll 2
  for (int jj = 0; jj < 2 * R + 2; ++jj) {
    const float vl = hbl[((vr0 + jj) << 5) + vc];
    const int wb = WOFF + 8 + jj;
#pragma unroll
    for (int i = 0; i < 2; ++i) l1s[i] += g.w[wb - i] * vl;
  }
}

__device__ __forceinline__ void load_tile(const float* __restrict__ p1,
                                          const float* __restrict__ p2,
                                          float* __restrict__ sS, float* __restrict__ sD,
                                          int t, int gx0, int gy0) {
#pragma unroll 1
  for (int e = 0; e < 2; ++e) {
    const int gidx = t + (e << 9);
    const int ly = gidx >> 4, lg = gidx & 15;
    const int gy = gy0 + ly;
    const int gx = gx0 + (lg << 2);
    float4 a = make_float4(0.f, 0.f, 0.f, 0.f);
    float4 b = make_float4(0.f, 0.f, 0.f, 0.f);
    if (gy >= 0 && gy < 512) {
      if (gx >= 0 && gx + 3 < 512) {
        a = *reinterpret_cast<const float4*>(&p1[(gy << 9) + gx]);
        b = *reinterpret_cast<const float4*>(&p2[(gy << 9) + gx]);
      } else {
        float* ap = reinterpret_cast<float*>(&a);
        float* bp = reinterpret_cast<float*>(&b);
#pragma unroll
        for (int u = 0; u < 4; ++u) {
          const int x = gx + u;
          if (x >= 0 && x < 512) { ap[u] = p1[(gy << 9) + x]; bp[u] = p2[(gy << 9) + x]; }
        }
      }
    }
    float4 s, d;
    s.x = a.x + b.x; s.y = a.y + b.y; s.z = a.z + b.z; s.w = a.w + b.w;
    d.x = a.x - b.x; d.y = a.y - b.y; d.z = a.z - b.z; d.w = a.w - b.w;
    const int off = (ly << 6) + ((lg ^ (ly & 7)) << 2);
    *reinterpret_cast<float4*>(&sS[off]) = s;
    *reinterpret_cast<float4*>(&sD[off]) = d;
  }
}

}  // namespace

extern "C" __global__ __launch_bounds__(512) void msssim_main(
    const float* __restrict__ img1, const float* __restrict__ img2,
    float* __restrict__ partial, GW g) {
  __shared__ __align__(16) float sS[4096];
  __shared__ __align__(16) float sD[4096];
  __shared__ __align__(16) float4 hb[2048];   // 32 KB; L1 aliases first 8 KB
  __shared__ float red[8];
  float* hbl = reinterpret_cast<float*>(hb);

  const int t = threadIdx.x;

  // XCD-contiguous swizzle: 2048 blocks / 8 XCDs -> XCD k owns batch image k.
  const int bid = (int)blockIdx.x + ((int)blockIdx.y << 4) + ((int)blockIdx.z << 8);
  const int swz = ((bid & 7) << 8) + (bid >> 3);
  const int bx = swz & 15, by = (swz >> 4) & 15, b = swz >> 8;

  const int gx0 = bx * 32 - 16;
  const int gy0 = by * 32 - 16;
  const int vc = t & 31;          // owned column
  const int vr0 = (t >> 5) << 1;  // owned row base (2 consecutive rows)

  float PI[2] = {1.f, 1.f};
  float lM[2] = {0.f, 0.f};
  float l1s[2] = {0.f, 0.f};

  // Channel 0: cs(s0.5)^3 * cs(s1)^2 ; L1 blur s8
  {
    const float* p1 = img1 + (((size_t)b * 3 + 0) << 18);
    const float* p2 = img2 + (((size_t)b * 3 + 0) << 18);
    load_tile(p1, p2, sS, sD, t, gx0, gy0);
    sweep4<2, W05, 3, false>(g, sS, sD, hb, t, vc, vr0, PI, lM);
    sweep4<4, W1, 2, false>(g, sS, sD, hb, t, vc, vr0, PI, lM);
    sweepL1<16, W8>(g, sD, hbl, t, vc, vr0, l1s);
  }
  // Channel 1: cs(s1)^1 * cs(s2)^3 * cs(s4)^1 ; L1 blur s8
  {
    const float* p1 = img1 + (((size_t)b * 3 + 1) << 18);
    const float* p2 = img2 + (((size_t)b * 3 + 1) << 18);
    load_tile(p1, p2, sS, sD, t, gx0, gy0);
    sweep4<4, W1, 1, false>(g, sS, sD, hb, t, vc, vr0, PI, lM);
    sweep4<9, W2, 3, false>(g, sS, sD, hb, t, vc, vr0, PI, lM);
    sweep4<13, W4, 1, false>(g, sS, sD, hb, t, vc, vr0, PI, lM);
    sweepL1<16, W8>(g, sD, hbl, t, vc, vr0, l1s);
  }
  // Channel 2: cs(s4)^2 * cs(s8)^3 + lM(s8) ; L1 blur s8
  {
    const float* p1 = img1 + (((size_t)b * 3 + 2) << 18);
    const float* p2 = img2 + (((size_t)b * 3 + 2) << 18);
    load_tile(p1, p2, sS, sD, t, gx0, gy0);
    sweep4<13, W4, 2, false>(g, sS, sD, hb, t, vc, vr0, PI, lM);
    sweep4<16, W8, 3, true>(g, sS, sD, hb, t, vc, vr0, PI, lM);
    sweepL1<16, W8>(g, sD, hbl, t, vc, vr0, l1s);
  }

  float s = 0.f;
#pragma unroll
  for (int i = 0; i < 2; ++i)
    s += 0.025f * (1.f - lM[i] * PI[i]) + 0.975f * (l1s[i] * (1.f / 3.f));

#pragma unroll
  for (int off = 32; off >= 1; off >>= 1) s += __shfl_down(s, off, 64);
  if ((t & 63) == 0) red[t >> 6] = s;
  __syncthreads();
  if (t == 0) {
    float tot = 0.f;
#pragma unroll
    for (int i = 0; i < 8; ++i) tot += red[i];
    partial[swz] = tot;
  }
}

extern "C" __global__ __launch_bounds__(256) void msssim_reduce(
    const float* __restrict__ partial, float* __restrict__ out, int n) {
  __shared__ float red[4];
  float s = 0.f;
  for (int i = threadIdx.x; i < n; i += 256) s += partial[i];
#pragma unroll
  for (int off = 32; off >= 1; off >>= 1) s += __shfl_down(s, off, 64);
  if ((threadIdx.x & 63) == 0) red[threadIdx.x >> 6] = s;
  __syncthreads();
  if (threadIdx.x == 0) {
    out[0] = (red[0] + red[1] + red[2] + red[3]) * (200.0f / 2097152.0f);
  }
}

extern "C" void kernel_launch(void* const* d_in, const int* in_sizes, int n_in,
                              void* d_out, int out_size, void* d_ws, size_t ws_size,
                              hipStream_t stream) {
  const float* img1 = (const float*)d_in[0];
  const float* img2 = (const float*)d_in[1];
  float* out = (float*)d_out;
  float* partial = (float*)d_ws;  // 2048 floats

  // Host-side padded weight tables (double-precision normalize over 2R+1 taps).
  GW g;
  {
    const double sig[5] = {0.5, 1.0, 2.0, 4.0, 8.0};
    const int R[5] = {2, 4, 9, 13, 16};
    const int off[5] = {W05, W1, W2, W4, W8};
    for (int i = 0; i < 5; ++i) {
      double tmp[17];
      double sum = 0.0;
      for (int k = 0; k <= R[i]; ++k) {
        tmp[k] = exp(-(double)(k * k) / (2.0 * sig[i] * sig[i]));
        sum += (k ? 2.0 : 1.0) * tmp[k];
      }
      const int len = 2 * R[i] + 17;
      for (int m = 0; m < len; ++m) {
        int d = m - 8 - R[i];
        if (d < 0) d = -d;
        g.w[off[i] + m] = (m >= 8 && m <= 8 + 2 * R[i]) ? (float)(tmp[d] / sum) : 0.0f;
      }
    }
  }

  dim3 grid(16, 16, 8);
  msssim_main<<<grid, dim3(512), 0, stream>>>(img1, img2, partial, g);
  msssim_reduce<<<1, dim3(256), 0, stream>>>(partial, out, 2048);
}

// Round 9
// 128.902 us; speedup vs baseline: 1.3123x; 1.1574x over previous
//
#include <hip/hip_runtime.h>
#include <math.h>

// Zero-padded symmetric weight tables: per sigma, layout is
// [8 zeros][w[R], ..., w[1], w[0], w[1], ..., w[R]][8 zeros]  (length 2R+17).
// Index m in [0, 2R] holds w[|m-R|] at table offset m+8. The pads absorb all
// out-of-range taps so the tap loops need no conditionals.
// Truncation (renormalized): sigma1 R4 / sigma2 R9 tails ~1e-6 (exact-ish);
// sigma4 R12 tail mass ~0.17% (largely cancels in cs/lc ratios);
// sigma8 R16 exact (also keeps the L1 path exact).
struct GW { float w[171]; };
constexpr int W05 = 0;    // sigma 0.5, R=2,  len 21
constexpr int W1  = 21;   // sigma 1,   R=4,  len 25
constexpr int W2  = 46;   // sigma 2,   R=9,  len 35
constexpr int W4  = 81;   // sigma 4,   R=12, len 41
constexpr int W8  = 122;  // sigma 8,   R=16, len 49

namespace {

constexpr float kC1 = 1e-4f;
constexpr float kC2 = 9e-4f;

// 512 threads/block, 32x32 output tile.
// LDS (64.5 KB -> 2 blocks/CU = 16 waves/CU):
//  sS/sD : [64][64] floats, float4-group g XOR'd by (row&7)   (16 KB each)
//  hb4   : [<=64 rows][32 slots] float4 (s,d,s2,d2), slot c^((c>>3)&3) (32 KB)
//  hbl   : L1 reuse of hb4: [64][32] floats, plain layout (8 KB).
// L1 fusion: blur is linear -> mean_ch blur(|d_ch|) = blur(sum_ch |d_ch|)/3.
// Each thread accumulates its 8 loaded |d| values per channel in registers,
// writes the sum into sD after the last sweep, then ONE sigma-8 L1 sweep.

// Horizontal pass, rows trimmed to NROWS=32+2R (hrow h = halo row h+16-R).
// One entry per thread (NE = NROWS*8 <= 512).
template<int R, int WOFF>
__device__ __forceinline__ void hpass4(const GW& g, const float* __restrict__ sS,
                                       const float* __restrict__ sD,
                                       float4* __restrict__ hb, int t) {
  constexpr int NROWS = 32 + 2 * R;
  constexpr int NE = NROWS * 8;
  constexpr int QS = (16 - R) & ~3;
  constexpr int NG = ((19 + R - QS) >> 2) + 1;
  if (t >= NE) return;
  const int hrow = t >> 3;
  const int cg = t & 7;
  const int srow = hrow + (16 - R);
  const int rx = srow & 7;
  const int rowbase = srow << 6;
  const int g0 = cg + (QS >> 2);
  float a0[4] = {0.f, 0.f, 0.f, 0.f}, a1[4] = {0.f, 0.f, 0.f, 0.f};
  float a2[4] = {0.f, 0.f, 0.f, 0.f}, a3[4] = {0.f, 0.f, 0.f, 0.f};
#pragma unroll 2
  for (int j = 0; j < NG; ++j) {
    const int off = rowbase + (((g0 + j) ^ rx) << 2);
    const int wb = WOFF + 8 + QS - 16 + R + 4 * j;  // + u - o; pads absorb ends
    const float4 s4 = *reinterpret_cast<const float4*>(&sS[off]);
    const float4 d4 = *reinterpret_cast<const float4*>(&sD[off]);
    const float* sp = reinterpret_cast<const float*>(&s4);
    const float* dp = reinterpret_cast<const float*>(&d4);
#pragma unroll
    for (int u = 0; u < 4; ++u) {
      const float sv = sp[u], dv = dp[u];
      const float s2 = sv * sv, d2 = dv * dv;
#pragma unroll
      for (int o = 0; o < 4; ++o) {
        const float wk = g.w[wb + u - o];
        a0[o] += wk * sv; a1[o] += wk * dv;
        a2[o] += wk * s2; a3[o] += wk * d2;
      }
    }
  }
  const int rb = hrow << 5;
#pragma unroll
  for (int o = 0; o < 4; ++o) {
    const int c = (cg << 2) + o;
    hb[rb + (c ^ ((c >> 3) & 3))] = make_float4(a0[o], a1[o], a2[o], a3[o]);
  }
}

// Vertical pass. Thread owns col vc = t&31, output rows vr0..vr0+1.
template<int R, int WOFF>
__device__ __forceinline__ void vpass4(const GW& g, const float4* __restrict__ hb,
                                       int vc, int vr0,
                                       float (&o0)[2], float (&o1)[2],
                                       float (&o2)[2], float (&o3)[2]) {
#pragma unroll
  for (int i = 0; i < 2; ++i) { o0[i] = o1[i] = o2[i] = o3[i] = 0.f; }
  const int fc = vc ^ ((vc >> 3) & 3);
#pragma unroll 2
  for (int jj = 0; jj < 2 * R + 2; ++jj) {
    const float4 v = hb[((vr0 + jj) << 5) + fc];
    const int wb = WOFF + 8 + jj;   // weight index: wb - i; pads absorb ends
#pragma unroll
    for (int i = 0; i < 2; ++i) {
      const float wk = g.w[wb - i];
      o0[i] += wk * v.x; o1[i] += wk * v.y;
      o2[i] += wk * v.z; o3[i] += wk * v.w;
    }
  }
}

template<int R, int WOFF, int MULT, bool DOLM>
__device__ __forceinline__ void sweep4(const GW& g,
    const float* sS, const float* sD, float4* hb, int t, int vc, int vr0,
    float (&PI)[2], float (&lM)[2]) {
  __syncthreads();                  // hb free, tile visible
  hpass4<R, WOFF>(g, sS, sD, hb, t);
  __syncthreads();
  float os[2], od[2], os2[2], od2[2];
  vpass4<R, WOFF>(g, hb, vc, vr0, os, od, os2, od2);
#pragma unroll
  for (int i = 0; i < 2; ++i) {
    const float vs = os2[i] - os[i] * os[i];   // Var(x+y)
    const float vd = od2[i] - od[i] * od[i];   // Var(x-y)
    const float cs = (0.5f * (vs - vd) + kC2) / (0.5f * (vs + vd) + kC2);
    float p = cs;
    if constexpr (MULT > 1) p *= cs;
    if constexpr (MULT > 2) p *= cs;
    PI[i] *= p;
    if constexpr (DOLM) {
      const float sa = os[i] * os[i], sb = od[i] * od[i];
      const float lc = (0.5f * (sa - sb) + kC1) / (0.5f * (sa + sb) + kC1);
      lM[i] = lc * lc * lc;
    }
  }
}

// L1 h-pass (sigma 8, R=16): blur of the pre-summed |d| tile in sD.
template<int R, int WOFF>
__device__ __forceinline__ void hpassL1(const GW& g, const float* __restrict__ sD,
                                        float* __restrict__ hbl, int t) {
  constexpr int QS = (16 - R) & ~3;
  constexpr int NG = ((19 + R - QS) >> 2) + 1;
  const int hrow = t >> 3;
  const int cg = t & 7;
  const int rx = hrow & 7;           // srow == hrow for R=16
  const int rowbase = hrow << 6;
  const int g0 = cg + (QS >> 2);
  float a0[4] = {0.f, 0.f, 0.f, 0.f};
#pragma unroll 2
  for (int j = 0; j < NG; ++j) {
    const int off = rowbase + (((g0 + j) ^ rx) << 2);
    const int wb = WOFF + 8 + QS - 16 + R + 4 * j;
    const float4 d4 = *reinterpret_cast<const float4*>(&sD[off]);
    const float* dp = reinterpret_cast<const float*>(&d4);
#pragma unroll
    for (int u = 0; u < 4; ++u) {
      const float av = dp[u];        // already >= 0 (sum of |d|)
#pragma unroll
      for (int o = 0; o < 4; ++o) a0[o] += g.w[wb + u - o] * av;
    }
  }
  *reinterpret_cast<float4*>(&hbl[(hrow << 5) + (cg << 2)]) =
      make_float4(a0[0], a0[1], a0[2], a0[3]);
}

// Fused L1 sweep: dump register-accumulated sum_ch |d| into sD (dead after the
// last hpass4), then one sigma-8 blur. Safe: all hpass4 reads of sD completed
// before the mid-sweep barrier of the preceding sweep4; hbl(=hb) writes happen
// after the barrier that ends the preceding vpass reads.
template<int R, int WOFF>
__device__ __forceinline__ void sweepL1_fused(const GW& g, float* sD, float* hbl,
                                              const float (&al1)[8], int t,
                                              int vc, int vr0, float (&l1s)[2]) {
#pragma unroll
  for (int e = 0; e < 2; ++e) {
    const int gidx = t + (e << 9);
    const int ly = gidx >> 4, lg = gidx & 15;
    const int off = (ly << 6) + ((lg ^ (ly & 7)) << 2);
    *reinterpret_cast<float4*>(&sD[off]) =
        make_float4(al1[4 * e], al1[4 * e + 1], al1[4 * e + 2], al1[4 * e + 3]);
  }
  __syncthreads();
  hpassL1<R, WOFF>(g, sD, hbl, t);
  __syncthreads();
#pragma unroll 2
  for (int jj = 0; jj < 2 * R + 2; ++jj) {
    const float vl = hbl[((vr0 + jj) << 5) + vc];
    const int wb = WOFF + 8 + jj;
#pragma unroll
    for (int i = 0; i < 2; ++i) l1s[i] += g.w[wb - i] * vl;
  }
}

__device__ __forceinline__ void load_tile(const float* __restrict__ p1,
                                          const float* __restrict__ p2,
                                          float* __restrict__ sS, float* __restrict__ sD,
                                          float (&al1)[8], int t, int gx0, int gy0) {
#pragma unroll 1
  for (int e = 0; e < 2; ++e) {
    const int gidx = t + (e << 9);
    const int ly = gidx >> 4, lg = gidx & 15;
    const int gy = gy0 + ly;
    const int gx = gx0 + (lg << 2);
    float4 a = make_float4(0.f, 0.f, 0.f, 0.f);
    float4 b = make_float4(0.f, 0.f, 0.f, 0.f);
    if (gy >= 0 && gy < 512) {
      if (gx >= 0 && gx + 3 < 512) {
        a = *reinterpret_cast<const float4*>(&p1[(gy << 9) + gx]);
        b = *reinterpret_cast<const float4*>(&p2[(gy << 9) + gx]);
      } else {
        float* ap = reinterpret_cast<float*>(&a);
        float* bp = reinterpret_cast<float*>(&b);
#pragma unroll
        for (int u = 0; u < 4; ++u) {
          const int x = gx + u;
          if (x >= 0 && x < 512) { ap[u] = p1[(gy << 9) + x]; bp[u] = p2[(gy << 9) + x]; }
        }
      }
    }
    float4 s, d;
    s.x = a.x + b.x; s.y = a.y + b.y; s.z = a.z + b.z; s.w = a.w + b.w;
    d.x = a.x - b.x; d.y = a.y - b.y; d.z = a.z - b.z; d.w = a.w - b.w;
    al1[4 * e + 0] += fabsf(d.x); al1[4 * e + 1] += fabsf(d.y);
    al1[4 * e + 2] += fabsf(d.z); al1[4 * e + 3] += fabsf(d.w);
    const int off = (ly << 6) + ((lg ^ (ly & 7)) << 2);
    *reinterpret_cast<float4*>(&sS[off]) = s;
    *reinterpret_cast<float4*>(&sD[off]) = d;
  }
}

}  // namespace

extern "C" __global__ __launch_bounds__(512) void msssim_main(
    const float* __restrict__ img1, const float* __restrict__ img2,
    float* __restrict__ partial, GW g) {
  __shared__ __align__(16) float sS[4096];
  __shared__ __align__(16) float sD[4096];
  __shared__ __align__(16) float4 hb[2048];   // 32 KB; L1 aliases first 8 KB
  __shared__ float red[8];
  float* hbl = reinterpret_cast<float*>(hb);

  const int t = threadIdx.x;

  // XCD-contiguous swizzle: 2048 blocks / 8 XCDs -> XCD k owns batch image k.
  const int bid = (int)blockIdx.x + ((int)blockIdx.y << 4) + ((int)blockIdx.z << 8);
  const int swz = ((bid & 7) << 8) + (bid >> 3);
  const int bx = swz & 15, by = (swz >> 4) & 15, b = swz >> 8;

  const int gx0 = bx * 32 - 16;
  const int gy0 = by * 32 - 16;
  const int vc = t & 31;          // owned column
  const int vr0 = (t >> 5) << 1;  // owned row base (2 consecutive rows)

  float PI[2] = {1.f, 1.f};
  float lM[2] = {0.f, 0.f};
  float l1s[2] = {0.f, 0.f};
  float al1[8] = {0.f, 0.f, 0.f, 0.f, 0.f, 0.f, 0.f, 0.f};

  // Channel 0: cs(s0.5)^3 * cs(s1)^2
  {
    const float* p1 = img1 + (((size_t)b * 3 + 0) << 18);
    const float* p2 = img2 + (((size_t)b * 3 + 0) << 18);
    load_tile(p1, p2, sS, sD, al1, t, gx0, gy0);
    sweep4<2, W05, 3, false>(g, sS, sD, hb, t, vc, vr0, PI, lM);
    sweep4<4, W1, 2, false>(g, sS, sD, hb, t, vc, vr0, PI, lM);
  }
  // Channel 1: cs(s1)^1 * cs(s2)^3 * cs(s4)^1
  {
    const float* p1 = img1 + (((size_t)b * 3 + 1) << 18);
    const float* p2 = img2 + (((size_t)b * 3 + 1) << 18);
    load_tile(p1, p2, sS, sD, al1, t, gx0, gy0);
    sweep4<4, W1, 1, false>(g, sS, sD, hb, t, vc, vr0, PI, lM);
    sweep4<9, W2, 3, false>(g, sS, sD, hb, t, vc, vr0, PI, lM);
    sweep4<12, W4, 1, false>(g, sS, sD, hb, t, vc, vr0, PI, lM);
  }
  // Channel 2: cs(s4)^2 * cs(s8)^3 + lM(s8)
  {
    const float* p1 = img1 + (((size_t)b * 3 + 2) << 18);
    const float* p2 = img2 + (((size_t)b * 3 + 2) << 18);
    load_tile(p1, p2, sS, sD, al1, t, gx0, gy0);
    sweep4<12, W4, 2, false>(g, sS, sD, hb, t, vc, vr0, PI, lM);
    sweep4<16, W8, 3, true>(g, sS, sD, hb, t, vc, vr0, PI, lM);
  }
  // Fused L1: one sigma-8 blur of sum_ch |d| (linearity of conv).
  sweepL1_fused<16, W8>(g, sD, hbl, al1, t, vc, vr0, l1s);

  float s = 0.f;
#pragma unroll
  for (int i = 0; i < 2; ++i)
    s += 0.025f * (1.f - lM[i] * PI[i]) + 0.975f * (l1s[i] * (1.f / 3.f));

#pragma unroll
  for (int off = 32; off >= 1; off >>= 1) s += __shfl_down(s, off, 64);
  if ((t & 63) == 0) red[t >> 6] = s;
  __syncthreads();
  if (t == 0) {
    float tot = 0.f;
#pragma unroll
    for (int i = 0; i < 8; ++i) tot += red[i];
    partial[swz] = tot;
  }
}

extern "C" __global__ __launch_bounds__(256) void msssim_reduce(
    const float* __restrict__ partial, float* __restrict__ out, int n) {
  __shared__ float red[4];
  float s = 0.f;
  for (int i = threadIdx.x; i < n; i += 256) s += partial[i];
#pragma unroll
  for (int off = 32; off >= 1; off >>= 1) s += __shfl_down(s, off, 64);
  if ((threadIdx.x & 63) == 0) red[threadIdx.x >> 6] = s;
  __syncthreads();
  if (threadIdx.x == 0) {
    out[0] = (red[0] + red[1] + red[2] + red[3]) * (200.0f / 2097152.0f);
  }
}

extern "C" void kernel_launch(void* const* d_in, const int* in_sizes, int n_in,
                              void* d_out, int out_size, void* d_ws, size_t ws_size,
                              hipStream_t stream) {
  const float* img1 = (const float*)d_in[0];
  const float* img2 = (const float*)d_in[1];
  float* out = (float*)d_out;
  float* partial = (float*)d_ws;  // 2048 floats

  // Host-side padded weight tables (double-precision normalize over 2R+1 taps).
  GW g;
  {
    const double sig[5] = {0.5, 1.0, 2.0, 4.0, 8.0};
    const int R[5] = {2, 4, 9, 12, 16};
    const int off[5] = {W05, W1, W2, W4, W8};
    for (int i = 0; i < 5; ++i) {
      double tmp[17];
      double sum = 0.0;
      for (int k = 0; k <= R[i]; ++k) {
        tmp[k] = exp(-(double)(k * k) / (2.0 * sig[i] * sig[i]));
        sum += (k ? 2.0 : 1.0) * tmp[k];
      }
      const int len = 2 * R[i] + 17;
      for (int m = 0; m < len; ++m) {
        int d = m - 8 - R[i];
        if (d < 0) d = -d;
        g.w[off[i] + m] = (m >= 8 && m <= 8 + 2 * R[i]) ? (float)(tmp[d] / sum) : 0.0f;
      }
    }
  }

  dim3 grid(16, 16, 8);
  msssim_main<<<grid, dim3(512), 0, stream>>>(img1, img2, partial, g);
  msssim_reduce<<<1, dim3(256), 0, stream>>>(partial, out, 2048);
}